// Round 1
// baseline (564.021 us; speedup 1.0000x reference)
//
#include <hip/hip_runtime.h>
#include <hip/hip_bf16.h>

__device__ __forceinline__ float lrelu(float x) { return x > 0.f ? x : 0.2f * x; }
__device__ __forceinline__ float blo(unsigned u) { return __uint_as_float(u << 16); }
__device__ __forceinline__ float bhi(unsigned u) { return __uint_as_float(u & 0xffff0000u); }

// ---------------------------------------------------------------------------
// K0: tiny prep — w_er[h0][i] = sum_d attn_r[h0,d]*W_dst[h0*32+d, i]  (256 vals)
//     Wn = softmax(fc_W, axis=1) (16 vals), fb = fc_b (4 vals)
// ---------------------------------------------------------------------------
__global__ void k_prep(const float* __restrict__ Wdst,
                       const float* __restrict__ attn_r,
                       const float* __restrict__ fcW,
                       const float* __restrict__ fcb,
                       float* __restrict__ w_er, float* __restrict__ Wn,
                       float* __restrict__ fb) {
    int t = threadIdx.x;
    if (t < 256) {
        int h0 = t >> 7, i = t & 127;
        float s = 0.f;
        for (int d = 0; d < 32; ++d)
            s += attn_r[h0 * 32 + d] * Wdst[(size_t)(h0 * 32 + d) * 128 + i];
        w_er[t] = s;
    }
    if (t < 16) {
        int oh = t >> 2, k = t & 3;
        float w[4], m = -1e30f;
        for (int j = 0; j < 4; ++j) {
            w[j] = fcW[oh * 4 + j];
            m = fmaxf(m, w[j]);
        }
        float s = 0.f;
        for (int j = 0; j < 4; ++j) s += __expf(w[j] - m);
        Wn[t] = __expf(w[k] - m) / s;
    }
    if (t < 4) fb[t] = fcb[t];
}

// ---------------------------------------------------------------------------
// Phase A: feat projection (bf16 out) + el  +  fused hist (1 edge/thread)
//          +  fused er (grid-stride, wave per node).
//   feat bf16 layout: node n has 128 bf16 = cols h1*64 + h0*32 + dd.
// ---------------------------------------------------------------------------
__global__ __launch_bounds__(256) void k_featA(
        const float* __restrict__ hier1, const float* __restrict__ Wsrc,
        const float* __restrict__ attn_l,
        const float* __restrict__ hier0, const float* __restrict__ w_er,
        const int* __restrict__ dstIdx,
        __hip_bfloat16* __restrict__ featb, float* __restrict__ el,
        float* __restrict__ er, int* __restrict__ deg,
        int nrows, int Ndst, int E) {
    __shared__ float4 Wlds[2048];   // [kk*64 + o]
    __shared__ float4 Hlds[1024];   // [r*32 + kk]
    int t = threadIdx.x;

    // --- fused hist: one edge per thread (independent of the rest) ---
    {
        int e = blockIdx.x * 256 + t;
        if (e < E) atomicAdd(&deg[dstIdx[e]], 1);
    }

    // --- feat tile ---
    const float4* W4 = reinterpret_cast<const float4*>(Wsrc);
#pragma unroll
    for (int j = 0; j < 8; ++j) {
        int g = t + j * 256;
        Wlds[(g & 31) * 64 + (g >> 5)] = W4[g];
    }
    int base = blockIdx.x * 32;
    const float4* H4 = reinterpret_cast<const float4*>(hier1);
#pragma unroll
    for (int j = 0; j < 4; ++j) {
        int idx = t + j * 256;
        int r = idx >> 5;
        if (base + r < nrows)
            Hlds[idx] = H4[(size_t)(base + r) * 32 + (idx & 31)];
    }
    __syncthreads();

    int w = t >> 6, o = t & 63;
    float al = attn_l[o];
    float acc[8];
#pragma unroll
    for (int j = 0; j < 8; ++j) acc[j] = 0.f;

    for (int kk = 0; kk < 32; ++kk) {
        float4 wv = Wlds[kk * 64 + o];
#pragma unroll
        for (int j = 0; j < 8; ++j) {
            float4 hv = Hlds[(w * 8 + j) * 32 + kk];
            acc[j] = fmaf(hv.x, wv.x,
                     fmaf(hv.y, wv.y,
                     fmaf(hv.z, wv.z,
                     fmaf(hv.w, wv.w, acc[j]))));
        }
    }

#pragma unroll
    for (int j = 0; j < 8; ++j) {
        int row = base + w * 8 + j;
        if (row < nrows) {
            // row = n*2 + h1 -> featb[n*128 + h1*64 + o]
            featb[((size_t)(row >> 1)) * 128 + (row & 1) * 64 + o] =
                __float2bfloat16(acc[j]);
            float v = acc[j] * al;
#pragma unroll
            for (int m = 16; m >= 1; m >>= 1) v += __shfl_xor(v, m, 64);
            if ((o & 31) == 0) el[row * 2 + (o >> 5)] = v;
        }
    }

    // --- fused er: wave per node, grid-stride ---
    int lane = t & 63;
    int gw = blockIdx.x * 4 + w;
    int nwaves = gridDim.x * 4;
    float2 w0 = *reinterpret_cast<const float2*>(w_er + lane * 2);
    float2 w1 = *reinterpret_cast<const float2*>(w_er + 128 + lane * 2);
    for (int node = gw; node < Ndst; node += nwaves) {
        float2 h = *reinterpret_cast<const float2*>(hier0 + (size_t)node * 128 + lane * 2);
        float p0 = h.x * w0.x + h.y * w0.y;
        float p1 = h.x * w1.x + h.y * w1.y;
#pragma unroll
        for (int m = 32; m >= 1; m >>= 1) {
            p0 += __shfl_xor(p0, m, 64);
            p1 += __shfl_xor(p1, m, 64);
        }
        if (lane == 0) {
            er[node * 2] = p0;
            er[node * 2 + 1] = p1;
        }
    }
}

// ---------------------------------------------------------------------------
// Slab alloc: per-wave prefix + one atomicAdd per wave (order irrelevant).
// ---------------------------------------------------------------------------
__global__ void k_alloc(const int* __restrict__ deg, int* __restrict__ off,
                        int* __restrict__ cursor, int* __restrict__ counter,
                        int N) {
    int d = blockIdx.x * blockDim.x + threadIdx.x;
    int lane = threadIdx.x & 63;
    int v = (d < N) ? deg[d] : 0;
    int inc = v;
#pragma unroll
    for (int m = 1; m < 64; m <<= 1) {
        int u = __shfl_up(inc, m, 64);
        if (lane >= m) inc += u;
    }
    int excl = inc - v;
    int base = 0;
    if (lane == 63) base = atomicAdd(counter, inc);
    base = __shfl(base, 63, 64);
    if (d < N) {
        off[d] = base + excl;
        cursor[d] = base + excl;
    }
}

__global__ void k_scatter(const int* __restrict__ src, const int* __restrict__ dst,
                          int* __restrict__ cursor, int* __restrict__ ssrc, int E) {
    int e = blockIdx.x * blockDim.x + threadIdx.x;
    if (e >= E) return;
    int pos = atomicAdd(&cursor[dst[e]], 1);
    ssrc[pos] = src[e];
}

// ---------------------------------------------------------------------------
// Gather + fused epilogue.  ONE WAVE per dst, FOUR edges per iteration.
//   Lane layout: q = lane>>4 owns edge (i+q); c = lane&15 owns bf16 cols
//   8c..8c+7 (one uint4 = 16B of the 256B feat row), all within k = c>>2.
//   Per group of 4 edges: 1 feat uint4 load + 1 el load + 1 ssrc prefetch
//   + 1 exp per lane (vs 3 VMEM + 1 exp PER EDGE before) -> 4x fewer VMEM
//   instructions, 4x the memory-level parallelism. Bytes unchanged.
//   Butterfly over lanes {c, c+16, c+32, c+48} merges the 4 edge-slots.
// ---------------------------------------------------------------------------
__global__ __launch_bounds__(256) void k_gather(
        const int* __restrict__ ssrc, const int* __restrict__ off,
        const int* __restrict__ deg,
        const float* __restrict__ el, const float* __restrict__ er,
        const uint4* __restrict__ feat4,
        const float* __restrict__ bias,
        const float* __restrict__ Wn, const float* __restrict__ fb,
        float* __restrict__ out, int Ndst, int E) {
    __shared__ float g[4][128];
    int t = threadIdx.x;
    int wv = t >> 6, lane = t & 63;
    int d = blockIdx.x * 4 + wv;
    bool valid = d < Ndst;

    int q = lane >> 4;          // edge slot within group of 4
    int c = lane & 15;          // 16B chunk: bf16 cols 8c..8c+7
    int k = c >> 2;             // h1*2 + h0 for these cols
    float erk = valid ? er[d * 2 + (k & 1)] : 0.f;
    int start = valid ? off[d] : 0;
    int n = valid ? deg[d] : 0;

    float a[8];
#pragma unroll
    for (int j = 0; j < 8; ++j) a[j] = 0.f;
    float den = 0.f;

    // prefetch this lane's edge-slot src one group ahead (clamped in-bounds)
    int ai = start + q;
    int s_pre = ssrc[ai < E ? ai : 0];
    for (int i = 0; i < n; i += 4) {
        int s = s_pre;
        int ni = start + i + 4 + q;
        s_pre = ssrc[ni < E ? ni : 0];          // next group's src (may be dead)
        bool ve = (i + q) < n;
        uint4 f = feat4[(size_t)s * 16 + c];    // 16B of the 256B feat row
        float eL = el[s * 4 + k];
        float ee = ve ? __expf(lrelu(eL + erk)) : 0.f;
        den += ee;
        a[0] = fmaf(ee, blo(f.x), a[0]);
        a[1] = fmaf(ee, bhi(f.x), a[1]);
        a[2] = fmaf(ee, blo(f.y), a[2]);
        a[3] = fmaf(ee, bhi(f.y), a[3]);
        a[4] = fmaf(ee, blo(f.z), a[4]);
        a[5] = fmaf(ee, bhi(f.z), a[5]);
        a[6] = fmaf(ee, blo(f.w), a[6]);
        a[7] = fmaf(ee, bhi(f.w), a[7]);
    }

    // merge the 4 edge-slots: lanes {c, c+16, c+32, c+48}
#pragma unroll
    for (int m = 16; m <= 32; m <<= 1) {
        den += __shfl_xor(den, m, 64);
#pragma unroll
        for (int j = 0; j < 8; ++j) a[j] += __shfl_xor(a[j], m, 64);
    }

    float inv = den > 0.f ? 1.f / den : 0.f;
    if (q == 0) {                               // lanes 0..15 hold full sums
        int h0 = k & 1, ddb = (c & 3) * 8;
#pragma unroll
        for (int j = 0; j < 8; ++j)
            g[wv][c * 8 + j] = a[j] * inv + bias[h0 * 32 + ddb + j];
    }
    __syncthreads();

    if (valid) {
        int dd = (lane & 15) * 2;
        int oh = lane >> 4;      // out cols 2l,2l+1 -> oh = (2l)>>5
        float r0 = fb[oh], r1 = r0;
#pragma unroll
        for (int kk = 0; kk < 4; ++kk) {
            float wgt = Wn[oh * 4 + kk];
            r0 = fmaf(g[wv][kk * 32 + dd], wgt, r0);
            r1 = fmaf(g[wv][kk * 32 + dd + 1], wgt, r1);
        }
        *reinterpret_cast<float2*>(out + (size_t)d * 128 + lane * 2) =
            make_float2(r0, r1);
    }
}

// ---------------------------------------------------------------------------
extern "C" void kernel_launch(void* const* d_in, const int* in_sizes, int n_in,
                              void* d_out, int out_size, void* d_ws, size_t ws_size,
                              hipStream_t stream) {
    (void)n_in; (void)out_size; (void)ws_size;
    const float* hier1  = (const float*)d_in[0];
    const float* hier0  = (const float*)d_in[1];
    const int*   srcIdx = (const int*)d_in[2];
    const int*   dstIdx = (const int*)d_in[3];
    const float* Wsrc   = (const float*)d_in[4];
    const float* Wdst   = (const float*)d_in[5];
    const float* attn_l = (const float*)d_in[6];
    const float* attn_r = (const float*)d_in[7];
    const float* bias   = (const float*)d_in[8];
    const float* fcW    = (const float*)d_in[9];
    const float* fcb    = (const float*)d_in[10];
    float* out = (float*)d_out;

    const int Nsrc  = in_sizes[0] / 256;  // N_SRC (H1=2, IN1=128)
    const int Ndst  = in_sizes[1] / 128;  // N_DST (IN0=128)
    const int E     = in_sizes[2];
    const int nrows = Nsrc * 2;           // N_SRC * H1

    // ws layout
    __hip_bfloat16* featb = (__hip_bfloat16*)d_ws;        // Nsrc*128 bf16
    float* el   = (float*)(featb + (size_t)Nsrc * 128);   // nrows*2
    float* er   = el   + (size_t)nrows * 2;               // Ndst*2
    float* w_er = er   + (size_t)Ndst * 2;                // 256
    float* Wn   = w_er + 256;                             // 16
    float* fb   = Wn + 16;                                // 4
    int*  deg     = (int*)(fb + 4);                       // Ndst
    int*  off     = deg + Ndst;                           // Ndst
    int*  cursor  = off + Ndst;                           // Ndst
    int*  counter = cursor + Ndst;                        // 1
    int*  ssrc    = counter + 1;                          // E

    hipMemsetAsync(deg, 0, (size_t)Ndst * sizeof(int), stream);
    hipMemsetAsync(counter, 0, sizeof(int), stream);

    k_prep<<<1, 256, 0, stream>>>(Wdst, attn_r, fcW, fcb, w_er, Wn, fb);

    int blocksA = (nrows + 31) / 32;
    int blocksE = (E + 255) / 256;
    if (blocksE > blocksA) blocksA = blocksE;
    k_featA<<<blocksA, 256, 0, stream>>>(hier1, Wsrc, attn_l, hier0, w_er,
                                         dstIdx, featb, el, er, deg,
                                         nrows, Ndst, E);

    k_alloc<<<(Ndst + 255) / 256, 256, 0, stream>>>(deg, off, cursor, counter, Ndst);

    k_scatter<<<(E + 255) / 256, 256, 0, stream>>>(srcIdx, dstIdx, cursor, ssrc, E);

    k_gather<<<(Ndst + 3) / 4, 256, 0, stream>>>(ssrc, off, deg, el, er,
                                                 (const uint4*)featb,
                                                 bias, Wn, fb, out, Ndst, E);
}

// Round 2
// 523.566 us; speedup vs baseline: 1.0773x; 1.0773x over previous
//
#include <hip/hip_runtime.h>
#include <hip/hip_bf16.h>

typedef __attribute__((ext_vector_type(8))) short short8_t;
typedef __attribute__((ext_vector_type(4))) float float4v;

__device__ __forceinline__ float lrelu(float x) { return x > 0.f ? x : 0.2f * x; }
__device__ __forceinline__ float blo(unsigned u) { return __uint_as_float(u << 16); }
__device__ __forceinline__ float bhi(unsigned u) { return __uint_as_float(u & 0xffff0000u); }

__device__ __forceinline__ short8_t mk8(unsigned a, unsigned b, unsigned c, unsigned d) {
    union { unsigned u[4]; short8_t s; } x;
    x.u[0] = a; x.u[1] = b; x.u[2] = c; x.u[3] = d;
    return x.s;
}

// ---------------------------------------------------------------------------
// K0: prep — w_er[h0][i] = sum_d attn_r[h0,d]*W_dst[h0*32+d, i]  (256 vals)
//     Wn = softmax(fc_W, axis=1) (16), fb = fc_b (4)
//     Wb_hi/Wb_lo: bf16 hi/lo split of W_src (64x128), row-major (o, k).
// ---------------------------------------------------------------------------
__global__ void k_prep(const float* __restrict__ Wdst,
                       const float* __restrict__ attn_r,
                       const float* __restrict__ fcW,
                       const float* __restrict__ fcb,
                       const float* __restrict__ Wsrc,
                       float* __restrict__ w_er, float* __restrict__ Wn,
                       float* __restrict__ fb,
                       unsigned short* __restrict__ Wb_hi,
                       unsigned short* __restrict__ Wb_lo) {
    int t = threadIdx.x;
    // W_src bf16 hi/lo split: 64*128 = 8192 elems, 32 per thread
#pragma unroll
    for (int j = 0; j < 32; ++j) {
        int i = t + j * 256;
        float x = Wsrc[i];
        unsigned hb = __float_as_uint(x) & 0xffff0000u;
        float lf = x - __uint_as_float(hb);
        Wb_hi[i] = (unsigned short)(hb >> 16);
        Wb_lo[i] = (unsigned short)(__float_as_uint(lf) >> 16);
    }
    {
        int h0 = t >> 7, i = t & 127;
        float s = 0.f;
        for (int d = 0; d < 32; ++d)
            s += attn_r[h0 * 32 + d] * Wdst[(size_t)(h0 * 32 + d) * 128 + i];
        w_er[t] = s;
    }
    if (t < 16) {
        int oh = t >> 2, k = t & 3;
        float w[4], m = -1e30f;
        for (int j = 0; j < 4; ++j) {
            w[j] = fcW[oh * 4 + j];
            m = fmaxf(m, w[j]);
        }
        float s = 0.f;
        for (int j = 0; j < 4; ++j) s += __expf(w[j] - m);
        Wn[t] = __expf(w[k] - m) / s;
    }
    if (t < 4) fb[t] = fcb[t];
}

// ---------------------------------------------------------------------------
// Phase A (MFMA): feat projection (bf16 out) + el  +  fused hist + fused er.
//   GEMM [nrows x 128] * [128 x 64] via mfma_f32_16x16x32_bf16, hi/lo split
//   (3 MFMA per tile-chunk => ~fp32 accuracy). No LDS at all.
//   Wave = one 16-row M-tile. A-frag: row = lane&15, k = (lane>>4)*8+j,
//   loaded from global fp32 + split in-register. B-frag: col(=W row) =
//   lane&15, same k, loaded from prep's bf16 Wb. D: col = lane&15,
//   row = (lane>>4)*4 + reg (HW-verified mapping).
// ---------------------------------------------------------------------------
__global__ __launch_bounds__(256) void k_featA(
        const float* __restrict__ hier1,
        const unsigned short* __restrict__ Wb_hi,
        const unsigned short* __restrict__ Wb_lo,
        const float* __restrict__ attn_l,
        const float* __restrict__ hier0, const float* __restrict__ w_er,
        const int* __restrict__ dstIdx,
        __hip_bfloat16* __restrict__ featb, float* __restrict__ el,
        float* __restrict__ er, int* __restrict__ deg,
        int nrows, int Ndst, int E, int ntiles) {
    int t = threadIdx.x;
    int w = t >> 6, lane = t & 63;

    // --- fused hist: grid-stride over edges ---
    for (int e = blockIdx.x * 256 + t; e < E; e += gridDim.x * 256)
        atomicAdd(&deg[dstIdx[e]], 1);

    int lr = lane & 15;   // A row / B col / D col
    int lg = lane >> 4;   // k sub-chunk group / D row group

    for (int tile = blockIdx.x * 4 + w; tile < ntiles; tile += gridDim.x * 4) {
        int m0 = tile * 16;

        // ---- A fragments: 16 rows x K=128, fp32 -> bf16 hi/lo in-register ----
        short8_t a_hi[4], a_lo[4];
        int row_l = m0 + lr;
        if (row_l >= nrows) row_l = nrows - 1;   // clamp (tail tile)
        const float* hrow = hier1 + (size_t)row_l * 128 + lg * 8;
#pragma unroll
        for (int kc = 0; kc < 4; ++kc) {
            float4 f0 = *reinterpret_cast<const float4*>(hrow + kc * 32);
            float4 f1 = *reinterpret_cast<const float4*>(hrow + kc * 32 + 4);
            float xs[8] = {f0.x, f0.y, f0.z, f0.w, f1.x, f1.y, f1.z, f1.w};
            unsigned h[4], l4[4];
#pragma unroll
            for (int p = 0; p < 4; ++p) {
                unsigned b0 = __float_as_uint(xs[2 * p]);
                unsigned b1 = __float_as_uint(xs[2 * p + 1]);
                unsigned h0b = b0 & 0xffff0000u, h1b = b1 & 0xffff0000u;
                h[p] = (h0b >> 16) | h1b;
                float l0 = xs[2 * p] - __uint_as_float(h0b);
                float l1 = xs[2 * p + 1] - __uint_as_float(h1b);
                l4[p] = (__float_as_uint(l0) >> 16) | (__float_as_uint(l1) & 0xffff0000u);
            }
            a_hi[kc] = mk8(h[0], h[1], h[2], h[3]);
            a_lo[kc] = mk8(l4[0], l4[1], l4[2], l4[3]);
        }

        // ---- 4 N-tiles of 16 cols, K=128 in 4 chunks, 3 MFMA each ----
        float4v acc[4];
#pragma unroll
        for (int n = 0; n < 4; ++n) acc[n] = (float4v){0.f, 0.f, 0.f, 0.f};
#pragma unroll
        for (int n = 0; n < 4; ++n) {
            const unsigned short* bh = Wb_hi + (size_t)(n * 16 + lr) * 128 + lg * 8;
            const unsigned short* bl = Wb_lo + (size_t)(n * 16 + lr) * 128 + lg * 8;
#pragma unroll
            for (int kc = 0; kc < 4; ++kc) {
                short8_t Bh = *reinterpret_cast<const short8_t*>(bh + kc * 32);
                short8_t Bl = *reinterpret_cast<const short8_t*>(bl + kc * 32);
                acc[n] = __builtin_amdgcn_mfma_f32_16x16x32_bf16(a_lo[kc], Bh, acc[n], 0, 0, 0);
                acc[n] = __builtin_amdgcn_mfma_f32_16x16x32_bf16(a_hi[kc], Bl, acc[n], 0, 0, 0);
                acc[n] = __builtin_amdgcn_mfma_f32_16x16x32_bf16(a_hi[kc], Bh, acc[n], 0, 0, 0);
            }
        }

        // ---- epilogue: featb store (bf16) + el partials ----
        float pe0[4] = {0.f, 0.f, 0.f, 0.f};   // h0 = 0 (cols 0..31)
        float pe1[4] = {0.f, 0.f, 0.f, 0.f};   // h0 = 1 (cols 32..63)
#pragma unroll
        for (int n = 0; n < 4; ++n) {
            float al = attn_l[n * 16 + lr];
#pragma unroll
            for (int r = 0; r < 4; ++r) {
                int row = m0 + lg * 4 + r;
                float v = acc[n][r];
                if (row < nrows)
                    featb[((size_t)(row >> 1)) * 128 + (row & 1) * 64 + n * 16 + lr] =
                        __float2bfloat16(v);
                if (n < 2) pe0[r] += v * al; else pe1[r] += v * al;
            }
        }
        // reduce over the 16 lanes sharing lg (masks 1,2,4,8)
#pragma unroll
        for (int m = 1; m <= 8; m <<= 1) {
#pragma unroll
            for (int r = 0; r < 4; ++r) {
                pe0[r] += __shfl_xor(pe0[r], m, 64);
                pe1[r] += __shfl_xor(pe1[r], m, 64);
            }
        }
        if (lr < 2) {
#pragma unroll
            for (int r = 0; r < 4; ++r) {
                int row = m0 + lg * 4 + r;
                float ev = lr ? pe1[r] : pe0[r];
                if (row < nrows) el[row * 2 + lr] = ev;
            }
        }
    }

    // --- fused er: wave per node, grid-stride ---
    int gw = blockIdx.x * 4 + w;
    int nwaves = gridDim.x * 4;
    float2 w0 = *reinterpret_cast<const float2*>(w_er + lane * 2);
    float2 w1 = *reinterpret_cast<const float2*>(w_er + 128 + lane * 2);
    for (int node = gw; node < Ndst; node += nwaves) {
        float2 h = *reinterpret_cast<const float2*>(hier0 + (size_t)node * 128 + lane * 2);
        float p0 = h.x * w0.x + h.y * w0.y;
        float p1 = h.x * w1.x + h.y * w1.y;
#pragma unroll
        for (int m = 32; m >= 1; m >>= 1) {
            p0 += __shfl_xor(p0, m, 64);
            p1 += __shfl_xor(p1, m, 64);
        }
        if (lane == 0) {
            er[node * 2] = p0;
            er[node * 2 + 1] = p1;
        }
    }
}

// ---------------------------------------------------------------------------
// Slab alloc: per-wave prefix + one atomicAdd per wave (order irrelevant).
// ---------------------------------------------------------------------------
__global__ void k_alloc(const int* __restrict__ deg, int* __restrict__ off,
                        int* __restrict__ cursor, int* __restrict__ counter,
                        int N) {
    int d = blockIdx.x * blockDim.x + threadIdx.x;
    int lane = threadIdx.x & 63;
    int v = (d < N) ? deg[d] : 0;
    int inc = v;
#pragma unroll
    for (int m = 1; m < 64; m <<= 1) {
        int u = __shfl_up(inc, m, 64);
        if (lane >= m) inc += u;
    }
    int excl = inc - v;
    int base = 0;
    if (lane == 63) base = atomicAdd(counter, inc);
    base = __shfl(base, 63, 64);
    if (d < N) {
        off[d] = base + excl;
        cursor[d] = base + excl;
    }
}

__global__ void k_scatter(const int* __restrict__ src, const int* __restrict__ dst,
                          int* __restrict__ cursor, int* __restrict__ ssrc, int E) {
    int e = blockIdx.x * blockDim.x + threadIdx.x;
    if (e >= E) return;
    int pos = atomicAdd(&cursor[dst[e]], 1);
    ssrc[pos] = src[e];
}

// ---------------------------------------------------------------------------
// Gather + fused epilogue.  ONE WAVE per dst, FOUR edges per iteration.
//   q = lane>>4 owns edge (i+q); c = lane&15 owns bf16 cols 8c..8c+7
//   (one uint4 = 16B of the 256B feat row), k = c>>2.
// ---------------------------------------------------------------------------
__global__ __launch_bounds__(256) void k_gather(
        const int* __restrict__ ssrc, const int* __restrict__ off,
        const int* __restrict__ deg,
        const float* __restrict__ el, const float* __restrict__ er,
        const uint4* __restrict__ feat4,
        const float* __restrict__ bias,
        const float* __restrict__ Wn, const float* __restrict__ fb,
        float* __restrict__ out, int Ndst, int E) {
    __shared__ float g[4][128];
    int t = threadIdx.x;
    int wv = t >> 6, lane = t & 63;
    int d = blockIdx.x * 4 + wv;
    bool valid = d < Ndst;

    int q = lane >> 4;          // edge slot within group of 4
    int c = lane & 15;          // 16B chunk: bf16 cols 8c..8c+7
    int k = c >> 2;             // h1*2 + h0 for these cols
    float erk = valid ? er[d * 2 + (k & 1)] : 0.f;
    int start = valid ? off[d] : 0;
    int n = valid ? deg[d] : 0;

    float a[8];
#pragma unroll
    for (int j = 0; j < 8; ++j) a[j] = 0.f;
    float den = 0.f;

    int ai = start + q;
    int s_pre = ssrc[ai < E ? ai : 0];
    for (int i = 0; i < n; i += 4) {
        int s = s_pre;
        int ni = start + i + 4 + q;
        s_pre = ssrc[ni < E ? ni : 0];
        bool ve = (i + q) < n;
        uint4 f = feat4[(size_t)s * 16 + c];
        float eL = el[s * 4 + k];
        float ee = ve ? __expf(lrelu(eL + erk)) : 0.f;
        den += ee;
        a[0] = fmaf(ee, blo(f.x), a[0]);
        a[1] = fmaf(ee, bhi(f.x), a[1]);
        a[2] = fmaf(ee, blo(f.y), a[2]);
        a[3] = fmaf(ee, bhi(f.y), a[3]);
        a[4] = fmaf(ee, blo(f.z), a[4]);
        a[5] = fmaf(ee, bhi(f.z), a[5]);
        a[6] = fmaf(ee, blo(f.w), a[6]);
        a[7] = fmaf(ee, bhi(f.w), a[7]);
    }

#pragma unroll
    for (int m = 16; m <= 32; m <<= 1) {
        den += __shfl_xor(den, m, 64);
#pragma unroll
        for (int j = 0; j < 8; ++j) a[j] += __shfl_xor(a[j], m, 64);
    }

    float inv = den > 0.f ? 1.f / den : 0.f;
    if (q == 0) {
        int h0 = k & 1, ddb = (c & 3) * 8;
#pragma unroll
        for (int j = 0; j < 8; ++j)
            g[wv][c * 8 + j] = a[j] * inv + bias[h0 * 32 + ddb + j];
    }
    __syncthreads();

    if (valid) {
        int dd = (lane & 15) * 2;
        int oh = lane >> 4;
        float r0 = fb[oh], r1 = r0;
#pragma unroll
        for (int kk = 0; kk < 4; ++kk) {
            float wgt = Wn[oh * 4 + kk];
            r0 = fmaf(g[wv][kk * 32 + dd], wgt, r0);
            r1 = fmaf(g[wv][kk * 32 + dd + 1], wgt, r1);
        }
        *reinterpret_cast<float2*>(out + (size_t)d * 128 + lane * 2) =
            make_float2(r0, r1);
    }
}

// ---------------------------------------------------------------------------
extern "C" void kernel_launch(void* const* d_in, const int* in_sizes, int n_in,
                              void* d_out, int out_size, void* d_ws, size_t ws_size,
                              hipStream_t stream) {
    (void)n_in; (void)out_size; (void)ws_size;
    const float* hier1  = (const float*)d_in[0];
    const float* hier0  = (const float*)d_in[1];
    const int*   srcIdx = (const int*)d_in[2];
    const int*   dstIdx = (const int*)d_in[3];
    const float* Wsrc   = (const float*)d_in[4];
    const float* Wdst   = (const float*)d_in[5];
    const float* attn_l = (const float*)d_in[6];
    const float* attn_r = (const float*)d_in[7];
    const float* bias   = (const float*)d_in[8];
    const float* fcW    = (const float*)d_in[9];
    const float* fcb    = (const float*)d_in[10];
    float* out = (float*)d_out;

    const int Nsrc  = in_sizes[0] / 256;  // N_SRC (H1=2, IN1=128)
    const int Ndst  = in_sizes[1] / 128;  // N_DST (IN0=128)
    const int E     = in_sizes[2];
    const int nrows = Nsrc * 2;           // N_SRC * H1
    const int ntiles = (nrows + 15) / 16;

    // ws layout
    __hip_bfloat16* featb = (__hip_bfloat16*)d_ws;              // Nsrc*128 bf16
    unsigned short* Wb_hi = (unsigned short*)(featb + (size_t)Nsrc * 128); // 8192
    unsigned short* Wb_lo = Wb_hi + 8192;                       // 8192
    float* el   = (float*)(Wb_lo + 8192);                       // nrows*2
    float* er   = el   + (size_t)nrows * 2;                     // Ndst*2
    float* w_er = er   + (size_t)Ndst * 2;                      // 256
    float* Wn   = w_er + 256;                                   // 16
    float* fb   = Wn + 16;                                      // 4
    int*  deg     = (int*)(fb + 4);                             // Ndst
    int*  off     = deg + Ndst;                                 // Ndst
    int*  cursor  = off + Ndst;                                 // Ndst
    int*  counter = cursor + Ndst;                              // 1
    int*  ssrc    = counter + 1;                                // E

    hipMemsetAsync(deg, 0, (size_t)Ndst * sizeof(int), stream);
    hipMemsetAsync(counter, 0, sizeof(int), stream);

    k_prep<<<1, 256, 0, stream>>>(Wdst, attn_r, fcW, fcb, Wsrc,
                                  w_er, Wn, fb, Wb_hi, Wb_lo);

    int blocksA = (ntiles + 3) / 4;
    if (blocksA < 1) blocksA = 1;
    k_featA<<<blocksA, 256, 0, stream>>>(hier1, Wb_hi, Wb_lo, attn_l,
                                         hier0, w_er, dstIdx,
                                         featb, el, er, deg,
                                         nrows, Ndst, E, ntiles);

    k_alloc<<<(Ndst + 255) / 256, 256, 0, stream>>>(deg, off, cursor, counter, Ndst);

    k_scatter<<<(E + 255) / 256, 256, 0, stream>>>(srcIdx, dstIdx, cursor, ssrc, E);

    k_gather<<<(Ndst + 3) / 4, 256, 0, stream>>>(ssrc, off, deg, el, er,
                                                 (const uint4*)featb,
                                                 bias, Wn, fb, out, Ndst, E);
}

// Round 4
// 486.820 us; speedup vs baseline: 1.1586x; 1.0755x over previous
//
#include <hip/hip_runtime.h>
#include <hip/hip_bf16.h>

typedef __attribute__((ext_vector_type(8))) short short8_t;
typedef __attribute__((ext_vector_type(4))) float float4v;

__device__ __forceinline__ float lrelu(float x) { return x > 0.f ? x : 0.2f * x; }
__device__ __forceinline__ float blo(unsigned u) { return __uint_as_float(u << 16); }
__device__ __forceinline__ float bhi(unsigned u) { return __uint_as_float(u & 0xffff0000u); }

__device__ __forceinline__ short8_t mk8(unsigned a, unsigned b, unsigned c, unsigned d) {
    union { unsigned u[4]; short8_t s; } x;
    x.u[0] = a; x.u[1] = b; x.u[2] = c; x.u[3] = d;
    return x.s;
}

// split 8 fp32 (two float4) into bf16 hi / lo fragments (packed 2-per-dword)
__device__ __forceinline__ void split8(const float4& f0, const float4& f1,
                                       short8_t& hi8, short8_t& lo8) {
    float xs[8] = {f0.x, f0.y, f0.z, f0.w, f1.x, f1.y, f1.z, f1.w};
    unsigned h[4], l4[4];
#pragma unroll
    for (int p = 0; p < 4; ++p) {
        unsigned b0 = __float_as_uint(xs[2 * p]);
        unsigned b1 = __float_as_uint(xs[2 * p + 1]);
        unsigned h0b = b0 & 0xffff0000u, h1b = b1 & 0xffff0000u;
        h[p] = (h0b >> 16) | h1b;
        float l0 = xs[2 * p] - __uint_as_float(h0b);
        float l1 = xs[2 * p + 1] - __uint_as_float(h1b);
        l4[p] = (__float_as_uint(l0) >> 16) | (__float_as_uint(l1) & 0xffff0000u);
    }
    hi8 = mk8(h[0], h[1], h[2], h[3]);
    lo8 = mk8(l4[0], l4[1], l4[2], l4[3]);
}

// ---------------------------------------------------------------------------
// K0: prep — w_er[h0*128+i] = sum_d attn_r[h0,d]*W_dst[h0*32+d, i]
//     Wn = softmax(fc_W, axis=1) (16), fb = fc_b (4)
//     Wb_hi/Wb_lo: bf16 hi/lo split of W_src (64x128), row-major (o, k).
// ---------------------------------------------------------------------------
__global__ void k_prep(const float* __restrict__ Wdst,
                       const float* __restrict__ attn_r,
                       const float* __restrict__ fcW,
                       const float* __restrict__ fcb,
                       const float* __restrict__ Wsrc,
                       float* __restrict__ w_er, float* __restrict__ Wn,
                       float* __restrict__ fb,
                       unsigned short* __restrict__ Wb_hi,
                       unsigned short* __restrict__ Wb_lo) {
    int t = threadIdx.x;
#pragma unroll
    for (int j = 0; j < 32; ++j) {
        int i = t + j * 256;
        float x = Wsrc[i];
        unsigned hb = __float_as_uint(x) & 0xffff0000u;
        float lf = x - __uint_as_float(hb);
        Wb_hi[i] = (unsigned short)(hb >> 16);
        Wb_lo[i] = (unsigned short)(__float_as_uint(lf) >> 16);
    }
    {
        int h0 = t >> 7, i = t & 127;
        float s = 0.f;
        for (int d = 0; d < 32; ++d)
            s += attn_r[h0 * 32 + d] * Wdst[(size_t)(h0 * 32 + d) * 128 + i];
        w_er[t] = s;
    }
    if (t < 16) {
        int oh = t >> 2, k = t & 3;
        float w[4], m = -1e30f;
        for (int j = 0; j < 4; ++j) {
            w[j] = fcW[oh * 4 + j];
            m = fmaxf(m, w[j]);
        }
        float s = 0.f;
        for (int j = 0; j < 4; ++j) s += __expf(w[j] - m);
        Wn[t] = __expf(w[k] - m) / s;
    }
    if (t < 4) fb[t] = fcb[t];
}

// ---------------------------------------------------------------------------
// hist: 1 edge/thread degree count (must precede k_alloc).
// ---------------------------------------------------------------------------
__global__ void k_hist(const int* __restrict__ dst, int* __restrict__ deg, int E) {
    int e = blockIdx.x * blockDim.x + threadIdx.x;
    if (e < E) atomicAdd(&deg[dst[e]], 1);
}

// ---------------------------------------------------------------------------
// Slab alloc: per-wave prefix + one atomicAdd per wave (order irrelevant).
// ---------------------------------------------------------------------------
__global__ void k_alloc(const int* __restrict__ deg, int* __restrict__ off,
                        int* __restrict__ cursor, int* __restrict__ counter,
                        int N) {
    int d = blockIdx.x * blockDim.x + threadIdx.x;
    int lane = threadIdx.x & 63;
    int v = (d < N) ? deg[d] : 0;
    int inc = v;
#pragma unroll
    for (int m = 1; m < 64; m <<= 1) {
        int u = __shfl_up(inc, m, 64);
        if (lane >= m) inc += u;
    }
    int excl = inc - v;
    int base = 0;
    if (lane == 63) base = atomicAdd(counter, inc);
    base = __shfl(base, 63, 64);
    if (d < N) {
        off[d] = base + excl;
        cursor[d] = base + excl;
    }
}

// ---------------------------------------------------------------------------
// Phase A (MFMA): feat projection (bf16 out) + el, with the edge SCATTER
// fused in (its atomic latency hides under the A-tile global loads).
//   GEMM [nrows x 128] * [128 x 64] via mfma_f32_16x16x32_bf16, hi/lo split.
//   Wave = one 16-row M-tile. No LDS.
// ---------------------------------------------------------------------------
__global__ __launch_bounds__(256) void k_featA(
        const float* __restrict__ hier1,
        const unsigned short* __restrict__ Wb_hi,
        const unsigned short* __restrict__ Wb_lo,
        const float* __restrict__ attn_l,
        const int* __restrict__ srcIdx, const int* __restrict__ dstIdx,
        int* __restrict__ cursor, int* __restrict__ ssrc,
        __hip_bfloat16* __restrict__ featb, float* __restrict__ el,
        int nrows, int E, int ntiles) {
    int t = threadIdx.x;
    int w = t >> 6, lane = t & 63;
    int lr = lane & 15;   // A row / B col / D col
    int lg = lane >> 4;   // k sub-chunk group / D row group

    int tile = blockIdx.x * 4 + w;
    bool hasTile = tile < ntiles;
    int m0 = tile * 16;

    // ---- issue A loads early (16 rows x K=128 fp32) ----
    float4 areg[8];
    if (hasTile) {
        int row_l = m0 + lr;
        if (row_l >= nrows) row_l = nrows - 1;
        const float* hrow = hier1 + (size_t)row_l * 128 + lg * 8;
#pragma unroll
        for (int kc = 0; kc < 4; ++kc) {
            areg[2 * kc]     = *reinterpret_cast<const float4*>(hrow + kc * 32);
            areg[2 * kc + 1] = *reinterpret_cast<const float4*>(hrow + kc * 32 + 4);
        }
    }

    // ---- fused scatter: grid-stride over edges (independent work that
    //      overlaps the A-load latency) ----
    for (int e = blockIdx.x * 256 + t; e < E; e += gridDim.x * 256) {
        int s = srcIdx[e];
        int d = dstIdx[e];
        int pos = atomicAdd(&cursor[d], 1);
        ssrc[pos] = s;
    }

    if (!hasTile) return;

    // ---- convert A to bf16 hi/lo fragments ----
    short8_t a_hi[4], a_lo[4];
#pragma unroll
    for (int kc = 0; kc < 4; ++kc)
        split8(areg[2 * kc], areg[2 * kc + 1], a_hi[kc], a_lo[kc]);

    // ---- 4 N-tiles of 16 cols, K=128 in 4 chunks, 3 MFMA each ----
    float4v acc[4];
#pragma unroll
    for (int n = 0; n < 4; ++n) acc[n] = (float4v){0.f, 0.f, 0.f, 0.f};
#pragma unroll
    for (int n = 0; n < 4; ++n) {
        const unsigned short* bh = Wb_hi + (size_t)(n * 16 + lr) * 128 + lg * 8;
        const unsigned short* bl = Wb_lo + (size_t)(n * 16 + lr) * 128 + lg * 8;
#pragma unroll
        for (int kc = 0; kc < 4; ++kc) {
            short8_t Bh = *reinterpret_cast<const short8_t*>(bh + kc * 32);
            short8_t Bl = *reinterpret_cast<const short8_t*>(bl + kc * 32);
            acc[n] = __builtin_amdgcn_mfma_f32_16x16x32_bf16(a_lo[kc], Bh, acc[n], 0, 0, 0);
            acc[n] = __builtin_amdgcn_mfma_f32_16x16x32_bf16(a_hi[kc], Bl, acc[n], 0, 0, 0);
            acc[n] = __builtin_amdgcn_mfma_f32_16x16x32_bf16(a_hi[kc], Bh, acc[n], 0, 0, 0);
        }
    }

    // ---- epilogue: featb store (bf16) + el partials ----
    float pe0[4] = {0.f, 0.f, 0.f, 0.f};
    float pe1[4] = {0.f, 0.f, 0.f, 0.f};
#pragma unroll
    for (int n = 0; n < 4; ++n) {
        float al = attn_l[n * 16 + lr];
#pragma unroll
        for (int r = 0; r < 4; ++r) {
            int row = m0 + lg * 4 + r;
            float v = acc[n][r];
            if (row < nrows)
                featb[((size_t)(row >> 1)) * 128 + (row & 1) * 64 + n * 16 + lr] =
                    __float2bfloat16(v);
            if (n < 2) pe0[r] += v * al; else pe1[r] += v * al;
        }
    }
#pragma unroll
    for (int m = 1; m <= 8; m <<= 1) {
#pragma unroll
        for (int r = 0; r < 4; ++r) {
            pe0[r] += __shfl_xor(pe0[r], m, 64);
            pe1[r] += __shfl_xor(pe1[r], m, 64);
        }
    }
    if (lr < 2) {
#pragma unroll
        for (int r = 0; r < 4; ++r) {
            int row = m0 + lg * 4 + r;
            float ev = lr ? pe1[r] : pe0[r];
            if (row < nrows) el[row * 2 + lr] = ev;
        }
    }
}

// ---------------------------------------------------------------------------
// er (MFMA): er[n,h0] = hier0[n,:] . w_er[h0,:].  [Ndst x 128] * [128 x 2]
//   B fragments loaded PER K-CHUNK (this was the R3 bug: B stuck at chunk 0).
//   D: row = node-in-tile = lg*4+r, col = h0 = lr (lr<2).
// ---------------------------------------------------------------------------
__global__ __launch_bounds__(256) void k_er(
        const float* __restrict__ hier0, const float* __restrict__ w_er,
        float* __restrict__ er, int Ndst, int ntilesE) {
    int t = threadIdx.x;
    int w = t >> 6, lane = t & 63;
    int lr = lane & 15, lg = lane >> 4;

    int tile = blockIdx.x * 4 + w;
    if (tile >= ntilesE) return;
    int m0 = tile * 16;

    // B fragments per K-chunk: col=lr (h0 for lr<2), k = kc*32 + lg*8 + j
    short8_t Bh[4], Bl[4];
#pragma unroll
    for (int kc = 0; kc < 4; ++kc) {
        Bh[kc] = mk8(0, 0, 0, 0);
        Bl[kc] = mk8(0, 0, 0, 0);
    }
    if (lr < 2) {
#pragma unroll
        for (int kc = 0; kc < 4; ++kc) {
            float4 f0 = *reinterpret_cast<const float4*>(w_er + lr * 128 + kc * 32 + lg * 8);
            float4 f1 = *reinterpret_cast<const float4*>(w_er + lr * 128 + kc * 32 + lg * 8 + 4);
            split8(f0, f1, Bh[kc], Bl[kc]);
        }
    }

    int node = m0 + lr;
    if (node >= Ndst) node = Ndst - 1;
    const float* hrow = hier0 + (size_t)node * 128 + lg * 8;

    float4v acc = (float4v){0.f, 0.f, 0.f, 0.f};
#pragma unroll
    for (int kc = 0; kc < 4; ++kc) {
        float4 f0 = *reinterpret_cast<const float4*>(hrow + kc * 32);
        float4 f1 = *reinterpret_cast<const float4*>(hrow + kc * 32 + 4);
        short8_t a_hi, a_lo;
        split8(f0, f1, a_hi, a_lo);
        acc = __builtin_amdgcn_mfma_f32_16x16x32_bf16(a_lo, Bh[kc], acc, 0, 0, 0);
        acc = __builtin_amdgcn_mfma_f32_16x16x32_bf16(a_hi, Bl[kc], acc, 0, 0, 0);
        acc = __builtin_amdgcn_mfma_f32_16x16x32_bf16(a_hi, Bh[kc], acc, 0, 0, 0);
    }

    if (lr < 2) {
#pragma unroll
        for (int r = 0; r < 4; ++r) {
            int nn = m0 + lg * 4 + r;
            if (nn < Ndst) er[nn * 2 + lr] = acc[r];
        }
    }
}

// ---------------------------------------------------------------------------
// Gather + fused epilogue.  ONE WAVE per dst, FOUR edges per iteration,
// software-pipelined 2 deep: feat/el for group i+1 issued before consuming
// group i; ssrc prefetched 2 groups ahead.
// ---------------------------------------------------------------------------
__global__ __launch_bounds__(256) void k_gather(
        const int* __restrict__ ssrc, const int* __restrict__ off,
        const int* __restrict__ deg,
        const float* __restrict__ el, const float* __restrict__ er,
        const uint4* __restrict__ feat4,
        const float* __restrict__ bias,
        const float* __restrict__ Wn, const float* __restrict__ fb,
        float* __restrict__ out, int Ndst, int E) {
    __shared__ float g[4][128];
    int t = threadIdx.x;
    int wv = t >> 6, lane = t & 63;
    int d = blockIdx.x * 4 + wv;
    bool valid = d < Ndst;

    int q = lane >> 4;          // edge slot within group of 4
    int c = lane & 15;          // 16B chunk: bf16 cols 8c..8c+7
    int k = c >> 2;             // h1*2 + h0 for these cols
    float erk = valid ? er[d * 2 + (k & 1)] : 0.f;
    int start = valid ? off[d] : 0;
    int n = valid ? deg[d] : 0;

    float a[8];
#pragma unroll
    for (int j = 0; j < 8; ++j) a[j] = 0.f;
    float den = 0.f;

    int base = start + q;
    int sA = ssrc[base < E ? base : 0];
    int sB = ssrc[(base + 4) < E ? (base + 4) : 0];
    uint4 fA = feat4[(size_t)sA * 16 + c];
    float eA = el[sA * 4 + k];

    for (int i = 0; i < n; i += 4) {
        // issue next group's loads before consuming current
        uint4 fB = feat4[(size_t)sB * 16 + c];
        float eB = el[sB * 4 + k];
        int nx = base + i + 8;
        int sC = ssrc[nx < E ? nx : 0];

        bool ve = (i + q) < n;
        float ee = ve ? __expf(lrelu(eA + erk)) : 0.f;
        den += ee;
        a[0] = fmaf(ee, blo(fA.x), a[0]);
        a[1] = fmaf(ee, bhi(fA.x), a[1]);
        a[2] = fmaf(ee, blo(fA.y), a[2]);
        a[3] = fmaf(ee, bhi(fA.y), a[3]);
        a[4] = fmaf(ee, blo(fA.z), a[4]);
        a[5] = fmaf(ee, bhi(fA.z), a[5]);
        a[6] = fmaf(ee, blo(fA.w), a[6]);
        a[7] = fmaf(ee, bhi(fA.w), a[7]);

        sB = sC; fA = fB; eA = eB;
    }

#pragma unroll
    for (int m = 16; m <= 32; m <<= 1) {
        den += __shfl_xor(den, m, 64);
#pragma unroll
        for (int j = 0; j < 8; ++j) a[j] += __shfl_xor(a[j], m, 64);
    }

    float inv = den > 0.f ? 1.f / den : 0.f;
    if (q == 0) {
        int h0 = k & 1, ddb = (c & 3) * 8;
#pragma unroll
        for (int j = 0; j < 8; ++j)
            g[wv][c * 8 + j] = a[j] * inv + bias[h0 * 32 + ddb + j];
    }
    __syncthreads();

    if (valid) {
        int dd = (lane & 15) * 2;
        int oh = lane >> 4;
        float r0 = fb[oh], r1 = r0;
#pragma unroll
        for (int kk = 0; kk < 4; ++kk) {
            float wgt = Wn[oh * 4 + kk];
            r0 = fmaf(g[wv][kk * 32 + dd], wgt, r0);
            r1 = fmaf(g[wv][kk * 32 + dd + 1], wgt, r1);
        }
        *reinterpret_cast<float2*>(out + (size_t)d * 128 + lane * 2) =
            make_float2(r0, r1);
    }
}

// ---------------------------------------------------------------------------
extern "C" void kernel_launch(void* const* d_in, const int* in_sizes, int n_in,
                              void* d_out, int out_size, void* d_ws, size_t ws_size,
                              hipStream_t stream) {
    (void)n_in; (void)out_size; (void)ws_size;
    const float* hier1  = (const float*)d_in[0];
    const float* hier0  = (const float*)d_in[1];
    const int*   srcIdx = (const int*)d_in[2];
    const int*   dstIdx = (const int*)d_in[3];
    const float* Wsrc   = (const float*)d_in[4];
    const float* Wdst   = (const float*)d_in[5];
    const float* attn_l = (const float*)d_in[6];
    const float* attn_r = (const float*)d_in[7];
    const float* bias   = (const float*)d_in[8];
    const float* fcW    = (const float*)d_in[9];
    const float* fcb    = (const float*)d_in[10];
    float* out = (float*)d_out;

    const int Nsrc  = in_sizes[0] / 256;  // N_SRC (H1=2, IN1=128)
    const int Ndst  = in_sizes[1] / 128;  // N_DST (IN0=128)
    const int E     = in_sizes[2];
    const int nrows = Nsrc * 2;           // N_SRC * H1
    const int ntiles  = (nrows + 15) / 16;
    const int ntilesE = (Ndst + 15) / 16;

    // ws layout
    __hip_bfloat16* featb = (__hip_bfloat16*)d_ws;              // Nsrc*128 bf16
    unsigned short* Wb_hi = (unsigned short*)(featb + (size_t)Nsrc * 128); // 8192
    unsigned short* Wb_lo = Wb_hi + 8192;                       // 8192
    float* el   = (float*)(Wb_lo + 8192);                       // nrows*2
    float* er   = el   + (size_t)nrows * 2;                     // Ndst*2
    float* w_er = er   + (size_t)Ndst * 2;                      // 256
    float* Wn   = w_er + 256;                                   // 16
    float* fb   = Wn + 16;                                      // 4
    int*  deg     = (int*)(fb + 4);                             // Ndst
    int*  off     = deg + Ndst;                                 // Ndst
    int*  cursor  = off + Ndst;                                 // Ndst
    int*  counter = cursor + Ndst;                              // 1
    int*  ssrc    = counter + 1;                                // E

    hipMemsetAsync(deg, 0, (size_t)Ndst * sizeof(int), stream);
    hipMemsetAsync(counter, 0, sizeof(int), stream);

    k_prep<<<1, 256, 0, stream>>>(Wdst, attn_r, fcW, fcb, Wsrc,
                                  w_er, Wn, fb, Wb_hi, Wb_lo);

    k_hist<<<(E + 255) / 256, 256, 0, stream>>>(dstIdx, deg, E);

    k_alloc<<<(Ndst + 255) / 256, 256, 0, stream>>>(deg, off, cursor, counter, Ndst);

    int blocksA = (ntiles + 3) / 4;
    if (blocksA < 1) blocksA = 1;
    k_featA<<<blocksA, 256, 0, stream>>>(hier1, Wb_hi, Wb_lo, attn_l,
                                         srcIdx, dstIdx, cursor, ssrc,
                                         featb, el, nrows, E, ntiles);

    k_er<<<(ntilesE + 3) / 4, 256, 0, stream>>>(hier0, w_er, er, Ndst, ntilesE);

    k_gather<<<(Ndst + 3) / 4, 256, 0, stream>>>(ssrc, off, deg, el, er,
                                                 (const uint4*)featb,
                                                 bias, Wn, fb, out, Ndst, E);
}

// Round 5
// 462.491 us; speedup vs baseline: 1.2195x; 1.0526x over previous
//
#include <hip/hip_runtime.h>
#include <hip/hip_bf16.h>

typedef __attribute__((ext_vector_type(8))) short short8_t;
typedef __attribute__((ext_vector_type(4))) float float4v;

__device__ __forceinline__ float lrelu(float x) { return x > 0.f ? x : 0.2f * x; }
__device__ __forceinline__ float blo(unsigned u) { return __uint_as_float(u << 16); }
__device__ __forceinline__ float bhi(unsigned u) { return __uint_as_float(u & 0xffff0000u); }

__device__ __forceinline__ short8_t mk8(unsigned a, unsigned b, unsigned c, unsigned d) {
    union { unsigned u[4]; short8_t s; } x;
    x.u[0] = a; x.u[1] = b; x.u[2] = c; x.u[3] = d;
    return x.s;
}

// split 8 fp32 (two float4) into bf16 hi / lo fragments (packed 2-per-dword)
__device__ __forceinline__ void split8(const float4& f0, const float4& f1,
                                       short8_t& hi8, short8_t& lo8) {
    float xs[8] = {f0.x, f0.y, f0.z, f0.w, f1.x, f1.y, f1.z, f1.w};
    unsigned h[4], l4[4];
#pragma unroll
    for (int p = 0; p < 4; ++p) {
        unsigned b0 = __float_as_uint(xs[2 * p]);
        unsigned b1 = __float_as_uint(xs[2 * p + 1]);
        unsigned h0b = b0 & 0xffff0000u, h1b = b1 & 0xffff0000u;
        h[p] = (h0b >> 16) | h1b;
        float l0 = xs[2 * p] - __uint_as_float(h0b);
        float l1 = xs[2 * p + 1] - __uint_as_float(h1b);
        l4[p] = (__float_as_uint(l0) >> 16) | (__float_as_uint(l1) & 0xffff0000u);
    }
    hi8 = mk8(h[0], h[1], h[2], h[3]);
    lo8 = mk8(l4[0], l4[1], l4[2], l4[3]);
}

// ---------------------------------------------------------------------------
// K0: prep — w_er[h0*128+i] = sum_d attn_r[h0,d]*W_dst[h0*32+d, i]
//     Wn = softmax(fc_W, axis=1) (16), fb = fc_b (4)
//     Wb_hi/Wb_lo: bf16 hi/lo split of W_src (64x128), row-major (o, k).
// ---------------------------------------------------------------------------
__global__ void k_prep(const float* __restrict__ Wdst,
                       const float* __restrict__ attn_r,
                       const float* __restrict__ fcW,
                       const float* __restrict__ fcb,
                       const float* __restrict__ Wsrc,
                       float* __restrict__ w_er, float* __restrict__ Wn,
                       float* __restrict__ fb,
                       unsigned short* __restrict__ Wb_hi,
                       unsigned short* __restrict__ Wb_lo) {
    int t = threadIdx.x;
#pragma unroll
    for (int j = 0; j < 32; ++j) {
        int i = t + j * 256;
        float x = Wsrc[i];
        unsigned hb = __float_as_uint(x) & 0xffff0000u;
        float lf = x - __uint_as_float(hb);
        Wb_hi[i] = (unsigned short)(hb >> 16);
        Wb_lo[i] = (unsigned short)(__float_as_uint(lf) >> 16);
    }
    {
        int h0 = t >> 7, i = t & 127;
        float s = 0.f;
        for (int d = 0; d < 32; ++d)
            s += attn_r[h0 * 32 + d] * Wdst[(size_t)(h0 * 32 + d) * 128 + i];
        w_er[t] = s;
    }
    if (t < 16) {
        int oh = t >> 2, k = t & 3;
        float w[4], m = -1e30f;
        for (int j = 0; j < 4; ++j) {
            w[j] = fcW[oh * 4 + j];
            m = fmaxf(m, w[j]);
        }
        float s = 0.f;
        for (int j = 0; j < 4; ++j) s += __expf(w[j] - m);
        Wn[t] = __expf(w[k] - m) / s;
    }
    if (t < 4) fb[t] = fcb[t];
}

// ---------------------------------------------------------------------------
// hist: 1 edge/thread degree count (must precede k_alloc).
// ---------------------------------------------------------------------------
__global__ void k_hist(const int* __restrict__ dst, int* __restrict__ deg, int E) {
    int e = blockIdx.x * blockDim.x + threadIdx.x;
    if (e < E) atomicAdd(&deg[dst[e]], 1);
}

// ---------------------------------------------------------------------------
// Slab alloc: per-wave prefix + one atomicAdd per wave (order irrelevant).
// ---------------------------------------------------------------------------
__global__ void k_alloc(const int* __restrict__ deg, int* __restrict__ off,
                        int* __restrict__ cursor, int* __restrict__ counter,
                        int N) {
    int d = blockIdx.x * blockDim.x + threadIdx.x;
    int lane = threadIdx.x & 63;
    int v = (d < N) ? deg[d] : 0;
    int inc = v;
#pragma unroll
    for (int m = 1; m < 64; m <<= 1) {
        int u = __shfl_up(inc, m, 64);
        if (lane >= m) inc += u;
    }
    int excl = inc - v;
    int base = 0;
    if (lane == 63) base = atomicAdd(counter, inc);
    base = __shfl(base, 63, 64);
    if (d < N) {
        off[d] = base + excl;
        cursor[d] = base + excl;
    }
}

// ---------------------------------------------------------------------------
// Phase A (MFMA): feat projection (bf16 out) + el  AND  er tiles, with the
// edge SCATTER fused in.  Order matters: srcIdx/dstIdx loads are issued
// FIRST so the atomic waits only on them (vmcnt(8)), not on the A-tile
// loads; the MFMA phase then overlaps the atomic+store latency.
//   tile < ntiles        : feat M-tile over hier1 rows -> featb + el
//   ntiles <= t < ntilesT: er tile over hier0 nodes    -> er
// ---------------------------------------------------------------------------
__global__ __launch_bounds__(256) void k_featA(
        const float* __restrict__ hier1, const float* __restrict__ hier0,
        const unsigned short* __restrict__ Wb_hi,
        const unsigned short* __restrict__ Wb_lo,
        const float* __restrict__ attn_l, const float* __restrict__ w_er,
        const int* __restrict__ srcIdx, const int* __restrict__ dstIdx,
        int* __restrict__ cursor, int* __restrict__ ssrc,
        __hip_bfloat16* __restrict__ featb, float* __restrict__ el,
        float* __restrict__ er,
        int nrows, int Ndst, int E, int ntiles, int ntilesT) {
    int t = threadIdx.x;
    int w = t >> 6, lane = t & 63;
    int lr = lane & 15;   // A row / B col / D col
    int lg = lane >> 4;   // k sub-chunk group / D row group

    // ---- edge indices FIRST (so the atomic below waits only on these) ----
    int e = blockIdx.x * 256 + t;
    bool hasE = e < E;
    int es = 0, ed = 0;
    if (hasE) { es = srcIdx[e]; ed = dstIdx[e]; }

    int tile = blockIdx.x * 4 + w;
    bool isFeat = tile < ntiles;
    bool isEr = (tile >= ntiles) && (tile < ntilesT);

    // ---- issue A loads (16 rows x K=128 fp32) ----
    float4 areg[8];
    if (isFeat || isEr) {
        const float* hrow;
        if (isFeat) {
            int row_l = tile * 16 + lr;
            if (row_l >= nrows) row_l = nrows - 1;
            hrow = hier1 + (size_t)row_l * 128 + lg * 8;
        } else {
            int node = (tile - ntiles) * 16 + lr;
            if (node >= Ndst) node = Ndst - 1;
            hrow = hier0 + (size_t)node * 128 + lg * 8;
        }
#pragma unroll
        for (int kc = 0; kc < 4; ++kc) {
            areg[2 * kc]     = *reinterpret_cast<const float4*>(hrow + kc * 32);
            areg[2 * kc + 1] = *reinterpret_cast<const float4*>(hrow + kc * 32 + 4);
        }
    }

    // ---- fused scatter (atomic latency hides under A loads / MFMA) ----
    if (hasE) {
        int pos = atomicAdd(&cursor[ed], 1);
        ssrc[pos] = es;
    }

    if (!(isFeat || isEr)) return;

    // ---- convert A to bf16 hi/lo fragments ----
    short8_t a_hi[4], a_lo[4];
#pragma unroll
    for (int kc = 0; kc < 4; ++kc)
        split8(areg[2 * kc], areg[2 * kc + 1], a_hi[kc], a_lo[kc]);

    if (isFeat) {
        int m0 = tile * 16;
        // ---- 4 N-tiles of 16 cols, K=128 in 4 chunks, 3 MFMA each ----
        float4v acc[4];
#pragma unroll
        for (int n = 0; n < 4; ++n) acc[n] = (float4v){0.f, 0.f, 0.f, 0.f};
#pragma unroll
        for (int n = 0; n < 4; ++n) {
            const unsigned short* bh = Wb_hi + (size_t)(n * 16 + lr) * 128 + lg * 8;
            const unsigned short* bl = Wb_lo + (size_t)(n * 16 + lr) * 128 + lg * 8;
#pragma unroll
            for (int kc = 0; kc < 4; ++kc) {
                short8_t Bh = *reinterpret_cast<const short8_t*>(bh + kc * 32);
                short8_t Bl = *reinterpret_cast<const short8_t*>(bl + kc * 32);
                acc[n] = __builtin_amdgcn_mfma_f32_16x16x32_bf16(a_lo[kc], Bh, acc[n], 0, 0, 0);
                acc[n] = __builtin_amdgcn_mfma_f32_16x16x32_bf16(a_hi[kc], Bl, acc[n], 0, 0, 0);
                acc[n] = __builtin_amdgcn_mfma_f32_16x16x32_bf16(a_hi[kc], Bh, acc[n], 0, 0, 0);
            }
        }

        // ---- epilogue: featb store (bf16) + el partials ----
        float pe0[4] = {0.f, 0.f, 0.f, 0.f};
        float pe1[4] = {0.f, 0.f, 0.f, 0.f};
#pragma unroll
        for (int n = 0; n < 4; ++n) {
            float al = attn_l[n * 16 + lr];
#pragma unroll
            for (int r = 0; r < 4; ++r) {
                int row = m0 + lg * 4 + r;
                float v = acc[n][r];
                if (row < nrows)
                    featb[((size_t)(row >> 1)) * 128 + (row & 1) * 64 + n * 16 + lr] =
                        __float2bfloat16(v);
                if (n < 2) pe0[r] += v * al; else pe1[r] += v * al;
            }
        }
#pragma unroll
        for (int m = 1; m <= 8; m <<= 1) {
#pragma unroll
            for (int r = 0; r < 4; ++r) {
                pe0[r] += __shfl_xor(pe0[r], m, 64);
                pe1[r] += __shfl_xor(pe1[r], m, 64);
            }
        }
        if (lr < 2) {
#pragma unroll
            for (int r = 0; r < 4; ++r) {
                int row = m0 + lg * 4 + r;
                float ev = lr ? pe1[r] : pe0[r];
                if (row < nrows) el[row * 2 + lr] = ev;
            }
        }
    } else {
        // ---- er tile: [16 x 128] * [128 x 2] with per-K-chunk B frags ----
        int m0 = (tile - ntiles) * 16;
        short8_t Bh[4], Bl[4];
#pragma unroll
        for (int kc = 0; kc < 4; ++kc) {
            Bh[kc] = mk8(0, 0, 0, 0);
            Bl[kc] = mk8(0, 0, 0, 0);
        }
        if (lr < 2) {
#pragma unroll
            for (int kc = 0; kc < 4; ++kc) {
                float4 f0 = *reinterpret_cast<const float4*>(w_er + lr * 128 + kc * 32 + lg * 8);
                float4 f1 = *reinterpret_cast<const float4*>(w_er + lr * 128 + kc * 32 + lg * 8 + 4);
                split8(f0, f1, Bh[kc], Bl[kc]);
            }
        }
        float4v acc = (float4v){0.f, 0.f, 0.f, 0.f};
#pragma unroll
        for (int kc = 0; kc < 4; ++kc) {
            acc = __builtin_amdgcn_mfma_f32_16x16x32_bf16(a_lo[kc], Bh[kc], acc, 0, 0, 0);
            acc = __builtin_amdgcn_mfma_f32_16x16x32_bf16(a_hi[kc], Bl[kc], acc, 0, 0, 0);
            acc = __builtin_amdgcn_mfma_f32_16x16x32_bf16(a_hi[kc], Bh[kc], acc, 0, 0, 0);
        }
        if (lr < 2) {
#pragma unroll
            for (int r = 0; r < 4; ++r) {
                int nn = m0 + lg * 4 + r;
                if (nn < Ndst) er[nn * 2 + lr] = acc[r];
            }
        }
    }
}

// ---------------------------------------------------------------------------
// Gather + fused epilogue.  ONE WAVE per dst, EIGHT edges per iteration,
// software-pipelined 2 deep (16 edges in flight).
//   q = lane>>3 owns edge (i+q); c = lane&7 owns bf16 cols 16c..16c+15
//   (two uint4 = 32B of the 256B feat row), k = c>>1.
//   Merge over the 8 edge slots: shuffle masks 8,16,32.
// ---------------------------------------------------------------------------
__global__ __launch_bounds__(256) void k_gather(
        const int* __restrict__ ssrc, const int* __restrict__ off,
        const int* __restrict__ deg,
        const float* __restrict__ el, const float* __restrict__ er,
        const uint4* __restrict__ feat4,
        const float* __restrict__ bias,
        const float* __restrict__ Wn, const float* __restrict__ fb,
        float* __restrict__ out, int Ndst, int E) {
    __shared__ float g[4][128];
    int t = threadIdx.x;
    int wv = t >> 6, lane = t & 63;
    int d = blockIdx.x * 4 + wv;
    bool valid = d < Ndst;

    int q = lane >> 3;          // edge slot within group of 8
    int c = lane & 7;           // 32B chunk: bf16 cols 16c..16c+15
    int k = c >> 1;             // h1*2 + h0 for these cols
    float erk = valid ? er[d * 2 + (k & 1)] : 0.f;
    int start = valid ? off[d] : 0;
    int n = valid ? deg[d] : 0;

    float a[16];
#pragma unroll
    for (int j = 0; j < 16; ++j) a[j] = 0.f;
    float den = 0.f;

    int base = start + q;
    int sA = ssrc[base < E ? base : 0];
    int sB = ssrc[(base + 8) < E ? (base + 8) : 0];
    uint4 fA0 = feat4[(size_t)sA * 16 + 2 * c];
    uint4 fA1 = feat4[(size_t)sA * 16 + 2 * c + 1];
    float eA = el[sA * 4 + k];

    for (int i = 0; i < n; i += 8) {
        // issue next group's loads before consuming current
        uint4 fB0 = feat4[(size_t)sB * 16 + 2 * c];
        uint4 fB1 = feat4[(size_t)sB * 16 + 2 * c + 1];
        float eB = el[sB * 4 + k];
        int nx = base + i + 16;
        int sC = ssrc[nx < E ? nx : 0];

        bool ve = (i + q) < n;
        float ee = ve ? __expf(lrelu(eA + erk)) : 0.f;
        den += ee;
        a[0]  = fmaf(ee, blo(fA0.x), a[0]);
        a[1]  = fmaf(ee, bhi(fA0.x), a[1]);
        a[2]  = fmaf(ee, blo(fA0.y), a[2]);
        a[3]  = fmaf(ee, bhi(fA0.y), a[3]);
        a[4]  = fmaf(ee, blo(fA0.z), a[4]);
        a[5]  = fmaf(ee, bhi(fA0.z), a[5]);
        a[6]  = fmaf(ee, blo(fA0.w), a[6]);
        a[7]  = fmaf(ee, bhi(fA0.w), a[7]);
        a[8]  = fmaf(ee, blo(fA1.x), a[8]);
        a[9]  = fmaf(ee, bhi(fA1.x), a[9]);
        a[10] = fmaf(ee, blo(fA1.y), a[10]);
        a[11] = fmaf(ee, bhi(fA1.y), a[11]);
        a[12] = fmaf(ee, blo(fA1.z), a[12]);
        a[13] = fmaf(ee, bhi(fA1.z), a[13]);
        a[14] = fmaf(ee, blo(fA1.w), a[14]);
        a[15] = fmaf(ee, bhi(fA1.w), a[15]);

        sB = sC; fA0 = fB0; fA1 = fB1; eA = eB;
    }

    // merge the 8 edge-slots: lanes {c, c+8, c+16, ..., c+56}
#pragma unroll
    for (int m = 8; m <= 32; m <<= 1) {
        den += __shfl_xor(den, m, 64);
#pragma unroll
        for (int j = 0; j < 16; ++j) a[j] += __shfl_xor(a[j], m, 64);
    }

    float inv = den > 0.f ? 1.f / den : 0.f;
    if (q == 0) {                         // lanes 0..7 hold full sums
        int h0 = k & 1;
        int db = (c & 1) * 16;            // offset within the 32-col k-group
#pragma unroll
        for (int j = 0; j < 16; ++j)
            g[wv][c * 16 + j] = a[j] * inv + bias[h0 * 32 + db + j];
    }
    __syncthreads();

    if (valid) {
        int dd = (lane & 15) * 2;
        int oh = lane >> 4;
        float r0 = fb[oh], r1 = r0;
#pragma unroll
        for (int kk = 0; kk < 4; ++kk) {
            float wgt = Wn[oh * 4 + kk];
            r0 = fmaf(g[wv][kk * 32 + dd], wgt, r0);
            r1 = fmaf(g[wv][kk * 32 + dd + 1], wgt, r1);
        }
        *reinterpret_cast<float2*>(out + (size_t)d * 128 + lane * 2) =
            make_float2(r0, r1);
    }
}

// ---------------------------------------------------------------------------
extern "C" void kernel_launch(void* const* d_in, const int* in_sizes, int n_in,
                              void* d_out, int out_size, void* d_ws, size_t ws_size,
                              hipStream_t stream) {
    (void)n_in; (void)out_size; (void)ws_size;
    const float* hier1  = (const float*)d_in[0];
    const float* hier0  = (const float*)d_in[1];
    const int*   srcIdx = (const int*)d_in[2];
    const int*   dstIdx = (const int*)d_in[3];
    const float* Wsrc   = (const float*)d_in[4];
    const float* Wdst   = (const float*)d_in[5];
    const float* attn_l = (const float*)d_in[6];
    const float* attn_r = (const float*)d_in[7];
    const float* bias   = (const float*)d_in[8];
    const float* fcW    = (const float*)d_in[9];
    const float* fcb    = (const float*)d_in[10];
    float* out = (float*)d_out;

    const int Nsrc  = in_sizes[0] / 256;  // N_SRC (H1=2, IN1=128)
    const int Ndst  = in_sizes[1] / 128;  // N_DST (IN0=128)
    const int E     = in_sizes[2];
    const int nrows = Nsrc * 2;           // N_SRC * H1
    const int ntiles  = (nrows + 15) / 16;
    const int ntilesE = (Ndst + 15) / 16;
    const int ntilesT = ntiles + ntilesE;

    // ws layout
    __hip_bfloat16* featb = (__hip_bfloat16*)d_ws;              // Nsrc*128 bf16
    unsigned short* Wb_hi = (unsigned short*)(featb + (size_t)Nsrc * 128); // 8192
    unsigned short* Wb_lo = Wb_hi + 8192;                       // 8192
    float* el   = (float*)(Wb_lo + 8192);                       // nrows*2
    float* er   = el   + (size_t)nrows * 2;                     // Ndst*2
    float* w_er = er   + (size_t)Ndst * 2;                      // 256
    float* Wn   = w_er + 256;                                   // 16
    float* fb   = Wn + 16;                                      // 4
    int*  deg     = (int*)(fb + 4);                             // Ndst
    int*  off     = deg + Ndst;                                 // Ndst
    int*  cursor  = off + Ndst;                                 // Ndst
    int*  counter = cursor + Ndst;                              // 1
    int*  ssrc    = counter + 1;                                // E

    hipMemsetAsync(deg, 0, (size_t)Ndst * sizeof(int), stream);
    hipMemsetAsync(counter, 0, sizeof(int), stream);

    k_prep<<<1, 256, 0, stream>>>(Wdst, attn_r, fcW, fcb, Wsrc,
                                  w_er, Wn, fb, Wb_hi, Wb_lo);

    k_hist<<<(E + 255) / 256, 256, 0, stream>>>(dstIdx, deg, E);

    k_alloc<<<(Ndst + 255) / 256, 256, 0, stream>>>(deg, off, cursor, counter, Ndst);

    int blocksA = (ntilesT + 3) / 4;
    int blocksE2 = (E + 255) / 256;
    if (blocksE2 > blocksA) blocksA = blocksE2;
    k_featA<<<blocksA, 256, 0, stream>>>(hier1, hier0, Wb_hi, Wb_lo,
                                         attn_l, w_er,
                                         srcIdx, dstIdx, cursor, ssrc,
                                         featb, el, er,
                                         nrows, Ndst, E, ntiles, ntilesT);

    k_gather<<<(Ndst + 3) / 4, 256, 0, stream>>>(ssrc, off, deg, el, er,
                                                 (const uint4*)featb,
                                                 bias, Wn, fb, out, Ndst, E);
}